// Round 1
// baseline (106.379 us; speedup 1.0000x reference)
//
#include <hip/hip_runtime.h>
#include <math.h>

#define NG 1024
#define IH 256
#define IW 256
#define NPIX (IH*IW)

// ---------------- Kernel 1: per-Gaussian preprocessing ----------------
__global__ __launch_bounds__(256) void k_pre(
    const float* __restrict__ means, const float* __restrict__ scales,
    const float* __restrict__ quats, const float* __restrict__ opacs,
    const float* __restrict__ sh0, const float* __restrict__ shn,
    const float* __restrict__ times, const float* __restrict__ durs,
    const float* __restrict__ vels, const float* __restrict__ tptr,
    const float* __restrict__ w2c, const float* __restrict__ intr,
    float* __restrict__ zc_out, float* __restrict__ raw)
{
    int g = blockIdx.x * 256 + threadIdx.x;
    if (g >= NG) return;
    const float t = tptr[0];
    // w2c is (1,4,4) row-major
    const float R00=w2c[0], R01=w2c[1], R02=w2c[2],  tx=w2c[3];
    const float R10=w2c[4], R11=w2c[5], R12=w2c[6],  ty=w2c[7];
    const float R20=w2c[8], R21=w2c[9], R22=w2c[10], tz=w2c[11];
    const float fx=intr[0], cx=intr[2], fy=intr[4], cy=intr[5];

    const float dt = t - times[g];
    const float mx = fmaf(dt, vels[g*3+0], means[g*3+0]);
    const float my = fmaf(dt, vels[g*3+1], means[g*3+1]);
    const float mz = fmaf(dt, vels[g*3+2], means[g*3+2]);

    // opacity = sigmoid(o) * exp(-0.5*(dt/exp(dur))^2)
    const float o = opacs[g];
    const float sig_o = 1.f / (1.f + __expf(-o));
    const float ratio = dt * __expf(-durs[g]);
    const float opac = sig_o * __expf(-0.5f * ratio * ratio);

    // camera-space position and projection
    const float xc = R00*mx + R01*my + R02*mz + tx;
    const float yc = R10*mx + R11*my + R12*mz + ty;
    const float zc = R20*mx + R21*my + R22*mz + tz;
    const float iz = 1.f / zc;
    const float u = fx*xc*iz + cx;
    const float v = fy*yc*iz + cy;

    // rotation from quaternion
    float qw=quats[g*4+0], qx=quats[g*4+1], qy=quats[g*4+2], qz=quats[g*4+3];
    const float qn = rsqrtf(qw*qw + qx*qx + qy*qy + qz*qz);
    qw*=qn; qx*=qn; qy*=qn; qz*=qn;
    const float sx = __expf(scales[g*3+0]);
    const float sy = __expf(scales[g*3+1]);
    const float sz = __expf(scales[g*3+2]);
    const float G00 = 1.f-2.f*(qy*qy+qz*qz), G01 = 2.f*(qx*qy-qw*qz), G02 = 2.f*(qx*qz+qw*qy);
    const float G10 = 2.f*(qx*qy+qw*qz), G11 = 1.f-2.f*(qx*qx+qz*qz), G12 = 2.f*(qy*qz-qw*qx);
    const float G20 = 2.f*(qx*qz-qw*qy), G21 = 2.f*(qy*qz+qw*qx), G22 = 1.f-2.f*(qx*qx+qy*qy);
    // M = G * diag(s)
    const float M00=G00*sx, M01=G01*sy, M02=G02*sz;
    const float M10=G10*sx, M11=G11*sy, M12=G12*sz;
    const float M20=G20*sx, M21=G21*sy, M22=G22*sz;
    // W = Rcw * M   (cov_cam = W W^T)
    const float W00=R00*M00+R01*M10+R02*M20, W01=R00*M01+R01*M11+R02*M21, W02=R00*M02+R01*M12+R02*M22;
    const float W10=R10*M00+R11*M10+R12*M20, W11=R10*M01+R11*M11+R12*M21, W12=R10*M02+R11*M12+R12*M22;
    const float W20=R20*M00+R21*M10+R22*M20, W21=R20*M01+R21*M11+R22*M21, W22=R20*M02+R21*M12+R22*M22;
    // T2 = J * W  (2x3), cov2d = T2 T2^T
    const float xdz = xc*iz, ydz = yc*iz;
    const float fxiz = fx*iz, fyiz = fy*iz;
    const float T00 = fxiz*(W00 - xdz*W20), T01 = fxiz*(W01 - xdz*W21), T02 = fxiz*(W02 - xdz*W22);
    const float T10 = fyiz*(W10 - ydz*W20), T11 = fyiz*(W11 - ydz*W21), T12 = fyiz*(W12 - ydz*W22);
    const float a = T00*T00 + T01*T01 + T02*T02 + 0.3f;
    const float b = T00*T10 + T01*T11 + T02*T12;
    const float c = T10*T10 + T11*T11 + T12*T12 + 0.3f;
    const float det = a*c - b*b;
    const float idet = 1.f / det;
    const float conA = c*idet, conB = -b*idet, conC = a*idet;

    const bool valid = (zc > 0.01f) && (det > 1e-12f);
    const float op_eff = valid ? opac : 0.f;
    // conservative cutoff: contribution requires op*exp(-sigma) >= 1/255
    const float smax = (op_eff * 255.f > 0.f) ? (logf(op_eff * 255.f) + 1e-4f) : -1e30f;

    // viewing direction (camera position = -Rcw^T tcw)
    const float cpx = -(R00*tx + R10*ty + R20*tz);
    const float cpy = -(R01*tx + R11*ty + R21*tz);
    const float cpz = -(R02*tx + R12*ty + R22*tz);
    float dx0 = mx-cpx, dy0 = my-cpy, dz0 = mz-cpz;
    const float dn = rsqrtf(dx0*dx0 + dy0*dy0 + dz0*dz0);
    const float X = dx0*dn, Y = dy0*dn, Z = dz0*dn;
    const float XX=X*X, YY=Y*Y, ZZ=Z*Z;

    float bs[16];
    bs[0]  = 0.28209479177387814f;
    bs[1]  = -0.4886025119029199f * Y;
    bs[2]  =  0.4886025119029199f * Z;
    bs[3]  = -0.4886025119029199f * X;
    bs[4]  =  1.0925484305920792f * X * Y;
    bs[5]  = -1.0925484305920792f * Y * Z;
    bs[6]  =  0.31539156525252005f * (2.f*ZZ - XX - YY);
    bs[7]  = -1.0925484305920792f * X * Z;
    bs[8]  =  0.5462742152960396f * (XX - YY);
    bs[9]  = -0.5900435899266435f * Y * (3.f*XX - YY);
    bs[10] =  2.890611442640554f  * X * Y * Z;
    bs[11] = -0.4570457994644658f * Y * (4.f*ZZ - XX - YY);
    bs[12] =  0.3731763325901154f * Z * (2.f*ZZ - 3.f*XX - 3.f*YY);
    bs[13] = -0.4570457994644658f * X * (4.f*ZZ - XX - YY);
    bs[14] =  1.445305721320277f  * Z * (XX - YY);
    bs[15] = -0.5900435899266435f * X * (XX - 3.f*YY);

    float cr = 0.5f, cg = 0.5f, cb = 0.5f;
    cr = fmaf(bs[0], sh0[g*3+0], cr);
    cg = fmaf(bs[0], sh0[g*3+1], cg);
    cb = fmaf(bs[0], sh0[g*3+2], cb);
    #pragma unroll
    for (int k = 1; k < 16; ++k) {
        const float* s = shn + g*45 + (k-1)*3;
        cr = fmaf(bs[k], s[0], cr);
        cg = fmaf(bs[k], s[1], cg);
        cb = fmaf(bs[k], s[2], cb);
    }
    cr = fmaxf(cr, 0.f); cg = fmaxf(cg, 0.f); cb = fmaxf(cb, 0.f);

    zc_out[g] = zc;
    float* r = raw + g*12;
    r[0] = u;            r[1] = v;    r[2] = 0.5f*conA; r[3] = conB;
    r[4] = 0.5f*conC;    r[5] = op_eff; r[6] = smax;    r[7] = cr;
    r[8] = cg;           r[9] = cb;   r[10] = 0.f;      r[11] = 0.f;
}

// ---------------- Kernel 2: stable depth rank + scatter ----------------
__global__ __launch_bounds__(64) void k_rank(
    const float* __restrict__ zc, const float* __restrict__ raw,
    float* __restrict__ sorted)
{
    const int g = blockIdx.x * 64 + threadIdx.x;   // 16 blocks x 64 = 1024
    const float myz = zc[g];
    const float4* __restrict__ z4 = (const float4*)zc;
    int rank = 0;
    #pragma unroll 4
    for (int j4 = 0; j4 < NG/4; ++j4) {
        const float4 z = z4[j4];
        const int j = j4 * 4;
        rank += (z.x < myz) || (z.x == myz && (j+0) < g);
        rank += (z.y < myz) || (z.y == myz && (j+1) < g);
        rank += (z.z < myz) || (z.z == myz && (j+2) < g);
        rank += (z.w < myz) || (z.w == myz && (j+3) < g);
    }
    const float4* src = (const float4*)(raw + g*12);
    float4* dst = (float4*)(sorted + rank*12);
    dst[0] = src[0]; dst[1] = src[1]; dst[2] = src[2];
}

// ---------------- Kernel 3: rasterize + composite ----------------
// Block = 256 threads = 4 waves. Each wave handles one depth-chunk of 256
// Gaussians for 64 consecutive pixels (lane = pixel). Chunk partials are
// combined associatively in LDS: color = c0 + T0*c1 + T0*T1*c2 + ...
__global__ __launch_bounds__(256) void k_raster(
    const float* __restrict__ sorted, float* __restrict__ out)
{
    __shared__ float4 lds[4][64];
    const int lane = threadIdx.x & 63;
    const int wv   = threadIdx.x >> 6;
    const int pix  = blockIdx.x * 64 + lane;
    const float px = (float)(pix & (IW-1)) + 0.5f;
    const float py = (float)(pix >> 8) + 0.5f;

    const float4* __restrict__ gp = (const float4*)sorted;
    // wave-uniform chunk base (helps uniformity analysis -> broadcast loads)
    const int g0 = __builtin_amdgcn_readfirstlane(wv) * (NG/4);

    float T = 1.f, cr = 0.f, cg = 0.f, cb = 0.f;
    #pragma unroll 2
    for (int i = 0; i < NG/4; ++i) {
        const int g = g0 + i;
        const float4 pa = gp[g*3+0];   // u, v, 0.5*conA, conB
        const float4 pb = gp[g*3+1];   // 0.5*conC, op, smax, col_r
        const float dx = px - pa.x;
        const float dy = py - pa.y;
        const float s1 = pa.z*dx + pa.w*dy;
        const float sigma = fmaf(dx, s1, pb.x*dy*dy);
        if (sigma >= 0.f && sigma <= pb.z) {
            float al = fminf(0.999f, pb.y * __expf(-sigma));
            if (al >= (1.f/255.f)) {
                const float4 pc = gp[g*3+2];  // col_g, col_b, pad, pad
                const float w = al * T;
                cr = fmaf(w, pb.w, cr);
                cg = fmaf(w, pc.x, cg);
                cb = fmaf(w, pc.y, cb);
                T -= w;                       // T *= (1-al)
            }
        }
    }
    lds[wv][lane] = make_float4(cr, cg, cb, T);
    __syncthreads();
    if (threadIdx.x < 64) {
        const float4 v0 = lds[0][lane];
        const float4 v1 = lds[1][lane];
        const float4 v2 = lds[2][lane];
        const float4 v3 = lds[3][lane];
        float r = v0.x, g2 = v0.y, b2 = v0.z, Tt = v0.w;
        r = fmaf(Tt, v1.x, r); g2 = fmaf(Tt, v1.y, g2); b2 = fmaf(Tt, v1.z, b2); Tt *= v1.w;
        r = fmaf(Tt, v2.x, r); g2 = fmaf(Tt, v2.y, g2); b2 = fmaf(Tt, v2.z, b2); Tt *= v2.w;
        r = fmaf(Tt, v3.x, r); g2 = fmaf(Tt, v3.y, g2); b2 = fmaf(Tt, v3.z, b2); Tt *= v3.w;
        const int p3 = pix * 3;
        out[p3+0] = fminf(fmaxf(r,  0.f), 1.f);
        out[p3+1] = fminf(fmaxf(g2, 0.f), 1.f);
        out[p3+2] = fminf(fmaxf(b2, 0.f), 1.f);
        out[NPIX*3 + pix] = 1.f - Tt;
    }
}

extern "C" void kernel_launch(void* const* d_in, const int* in_sizes, int n_in,
                              void* d_out, int out_size, void* d_ws, size_t ws_size,
                              hipStream_t stream) {
    const float* means  = (const float*)d_in[0];
    const float* scales = (const float*)d_in[1];
    const float* quats  = (const float*)d_in[2];
    const float* opacs  = (const float*)d_in[3];
    const float* sh0    = (const float*)d_in[4];
    const float* shn    = (const float*)d_in[5];
    const float* times  = (const float*)d_in[6];
    const float* durs   = (const float*)d_in[7];
    const float* vels   = (const float*)d_in[8];
    const float* tptr   = (const float*)d_in[9];
    const float* w2c    = (const float*)d_in[10];
    const float* intr   = (const float*)d_in[11];

    float* ws     = (float*)d_ws;
    float* zc     = ws;                    // 1024 floats
    float* raw    = ws + 1024;             // 1024*12 floats
    float* sorted = ws + 1024 + 12*NG;     // 1024*12 floats

    hipLaunchKernelGGL(k_pre, dim3(4), dim3(256), 0, stream,
                       means, scales, quats, opacs, sh0, shn,
                       times, durs, vels, tptr, w2c, intr, zc, raw);
    hipLaunchKernelGGL(k_rank, dim3(16), dim3(64), 0, stream, zc, raw, sorted);
    hipLaunchKernelGGL(k_raster, dim3(NPIX/64), dim3(256), 0, stream,
                       sorted, (float*)d_out);
}

// Round 2
// 20.457 us; speedup vs baseline: 5.2002x; 5.2002x over previous
//
#include <hip/hip_runtime.h>
#include <math.h>

#define NG 1024
#define IH 256
#define IW 256
#define NPIX (IH*IW)

// ---------------- Kernel 1: per-Gaussian preprocessing ----------------
__global__ __launch_bounds__(64) void k_pre(
    const float* __restrict__ means, const float* __restrict__ scales,
    const float* __restrict__ quats, const float* __restrict__ opacs,
    const float* __restrict__ sh0, const float* __restrict__ shn,
    const float* __restrict__ times, const float* __restrict__ durs,
    const float* __restrict__ vels, const float* __restrict__ tptr,
    const float* __restrict__ w2c, const float* __restrict__ intr,
    float* __restrict__ zc_out, float* __restrict__ raw)
{
    int g = blockIdx.x * 64 + threadIdx.x;
    if (g >= NG) return;
    const float t = tptr[0];
    // w2c is (1,4,4) row-major
    const float R00=w2c[0], R01=w2c[1], R02=w2c[2],  tx=w2c[3];
    const float R10=w2c[4], R11=w2c[5], R12=w2c[6],  ty=w2c[7];
    const float R20=w2c[8], R21=w2c[9], R22=w2c[10], tz=w2c[11];
    const float fx=intr[0], cx=intr[2], fy=intr[4], cy=intr[5];

    const float dt = t - times[g];
    const float mx = fmaf(dt, vels[g*3+0], means[g*3+0]);
    const float my = fmaf(dt, vels[g*3+1], means[g*3+1]);
    const float mz = fmaf(dt, vels[g*3+2], means[g*3+2]);

    // opacity = sigmoid(o) * exp(-0.5*(dt/exp(dur))^2)
    const float o = opacs[g];
    const float sig_o = 1.f / (1.f + __expf(-o));
    const float ratio = dt * __expf(-durs[g]);
    const float opac = sig_o * __expf(-0.5f * ratio * ratio);

    // camera-space position and projection
    const float xc = R00*mx + R01*my + R02*mz + tx;
    const float yc = R10*mx + R11*my + R12*mz + ty;
    const float zc = R20*mx + R21*my + R22*mz + tz;
    const float iz = 1.f / zc;
    const float u = fx*xc*iz + cx;
    const float v = fy*yc*iz + cy;

    // rotation from quaternion
    float qw=quats[g*4+0], qx=quats[g*4+1], qy=quats[g*4+2], qz=quats[g*4+3];
    const float qn = rsqrtf(qw*qw + qx*qx + qy*qy + qz*qz);
    qw*=qn; qx*=qn; qy*=qn; qz*=qn;
    const float sx = __expf(scales[g*3+0]);
    const float sy = __expf(scales[g*3+1]);
    const float sz = __expf(scales[g*3+2]);
    const float G00 = 1.f-2.f*(qy*qy+qz*qz), G01 = 2.f*(qx*qy-qw*qz), G02 = 2.f*(qx*qz+qw*qy);
    const float G10 = 2.f*(qx*qy+qw*qz), G11 = 1.f-2.f*(qx*qx+qz*qz), G12 = 2.f*(qy*qz-qw*qx);
    const float G20 = 2.f*(qx*qz-qw*qy), G21 = 2.f*(qy*qz+qw*qx), G22 = 1.f-2.f*(qx*qx+qy*qy);
    // M = G * diag(s)
    const float M00=G00*sx, M01=G01*sy, M02=G02*sz;
    const float M10=G10*sx, M11=G11*sy, M12=G12*sz;
    const float M20=G20*sx, M21=G21*sy, M22=G22*sz;
    // W = Rcw * M   (cov_cam = W W^T)
    const float W00=R00*M00+R01*M10+R02*M20, W01=R00*M01+R01*M11+R02*M21, W02=R00*M02+R01*M12+R02*M22;
    const float W10=R10*M00+R11*M10+R12*M20, W11=R10*M01+R11*M11+R12*M21, W12=R10*M02+R11*M12+R12*M22;
    const float W20=R20*M00+R21*M10+R22*M20, W21=R20*M01+R21*M11+R22*M21, W22=R20*M02+R21*M12+R22*M22;
    // T2 = J * W  (2x3), cov2d = T2 T2^T
    const float xdz = xc*iz, ydz = yc*iz;
    const float fxiz = fx*iz, fyiz = fy*iz;
    const float T00 = fxiz*(W00 - xdz*W20), T01 = fxiz*(W01 - xdz*W21), T02 = fxiz*(W02 - xdz*W22);
    const float T10 = fyiz*(W10 - ydz*W20), T11 = fyiz*(W11 - ydz*W21), T12 = fyiz*(W12 - ydz*W22);
    const float a = T00*T00 + T01*T01 + T02*T02 + 0.3f;
    const float b = T00*T10 + T01*T11 + T02*T12;
    const float c = T10*T10 + T11*T11 + T12*T12 + 0.3f;
    const float det = a*c - b*b;
    const float idet = 1.f / det;
    const float conA = c*idet, conB = -b*idet, conC = a*idet;

    const bool valid = (zc > 0.01f) && (det > 1e-12f);
    const float op_eff = valid ? opac : 0.f;
    // contribution requires op*exp(-sigma) >= 1/255  <=>  sigma <= log(255*op)
    const float smax = (op_eff * 255.f > 0.f) ? (logf(op_eff * 255.f) + 1e-4f) : -1e30f;
    // bbox of the {sigma <= smax} ellipse: |dx| <= sqrt(2*smax*a), |dy| <= sqrt(2*smax*c)
    float rx, ry;
    if (smax > 0.f) {
        rx = sqrtf(2.f * smax * a) + 0.01f;
        ry = sqrtf(2.f * smax * c) + 0.01f;
    } else {
        rx = -1e30f; ry = -1e30f;   // never passes the strip test
    }

    // viewing direction (camera position = -Rcw^T tcw)
    const float cpx = -(R00*tx + R10*ty + R20*tz);
    const float cpy = -(R01*tx + R11*ty + R21*tz);
    const float cpz = -(R02*tx + R12*ty + R22*tz);
    float dx0 = mx-cpx, dy0 = my-cpy, dz0 = mz-cpz;
    const float dn = rsqrtf(dx0*dx0 + dy0*dy0 + dz0*dz0);
    const float X = dx0*dn, Y = dy0*dn, Z = dz0*dn;
    const float XX=X*X, YY=Y*Y, ZZ=Z*Z;

    float bs[16];
    bs[0]  = 0.28209479177387814f;
    bs[1]  = -0.4886025119029199f * Y;
    bs[2]  =  0.4886025119029199f * Z;
    bs[3]  = -0.4886025119029199f * X;
    bs[4]  =  1.0925484305920792f * X * Y;
    bs[5]  = -1.0925484305920792f * Y * Z;
    bs[6]  =  0.31539156525252005f * (2.f*ZZ - XX - YY);
    bs[7]  = -1.0925484305920792f * X * Z;
    bs[8]  =  0.5462742152960396f * (XX - YY);
    bs[9]  = -0.5900435899266435f * Y * (3.f*XX - YY);
    bs[10] =  2.890611442640554f  * X * Y * Z;
    bs[11] = -0.4570457994644658f * Y * (4.f*ZZ - XX - YY);
    bs[12] =  0.3731763325901154f * Z * (2.f*ZZ - 3.f*XX - 3.f*YY);
    bs[13] = -0.4570457994644658f * X * (4.f*ZZ - XX - YY);
    bs[14] =  1.445305721320277f  * Z * (XX - YY);
    bs[15] = -0.5900435899266435f * X * (XX - 3.f*YY);

    float cr = 0.5f, cg = 0.5f, cb = 0.5f;
    cr = fmaf(bs[0], sh0[g*3+0], cr);
    cg = fmaf(bs[0], sh0[g*3+1], cg);
    cb = fmaf(bs[0], sh0[g*3+2], cb);
    #pragma unroll
    for (int k = 1; k < 16; ++k) {
        const float* s = shn + g*45 + (k-1)*3;
        cr = fmaf(bs[k], s[0], cr);
        cg = fmaf(bs[k], s[1], cg);
        cb = fmaf(bs[k], s[2], cb);
    }
    cr = fmaxf(cr, 0.f); cg = fmaxf(cg, 0.f); cb = fmaxf(cb, 0.f);

    zc_out[g] = zc;
    float* r = raw + g*12;
    r[0] = u;            r[1] = v;      r[2] = 0.5f*conA; r[3] = conB;
    r[4] = 0.5f*conC;    r[5] = op_eff; r[6] = smax;      r[7] = cr;
    r[8] = cg;           r[9] = cb;     r[10] = rx;       r[11] = ry;
}

// ---------------- Kernel 2: stable depth rank + scatter ----------------
// One wave per Gaussian; rank via 16 coalesced-load + ballot + popcount steps.
__global__ __launch_bounds__(64) void k_rank(
    const float* __restrict__ zc, const float* __restrict__ raw,
    float* __restrict__ sorted)
{
    const int g = blockIdx.x;            // 1024 blocks x 64 threads
    const int lane = threadIdx.x;
    const float myz = zc[g];
    int cnt = 0;
    #pragma unroll
    for (int k = 0; k < 16; ++k) {
        const int j = k*64 + lane;
        const float z = zc[j];
        const bool lt = (z < myz) || (z == myz && j < g);
        cnt += (int)__popcll(__ballot(lt));
    }
    // cnt is wave-uniform = stable ascending rank of g
    if (lane < 12) sorted[cnt*12 + lane] = raw[g*12 + lane];
}

// ---------------- Kernel 3: rasterize + composite ----------------
// Block = 256 threads = 4 waves. Each wave handles one depth-chunk of 256
// Gaussians for 64 consecutive pixels of one row (lane = pixel).
// Phase 0: ballot the chunk against the strip's bbox -> 4 u64 masks (SGPRs).
// Phase 1: walk set bits in order (exact front-to-back), composite.
// Chunk partials combined associatively in LDS: c = c0 + T0*c1 + T0*T1*c2 + ...
__global__ __launch_bounds__(256) void k_raster(
    const float* __restrict__ sorted, float* __restrict__ out)
{
    __shared__ float4 lds[4][64];
    const int lane = threadIdx.x & 63;
    const int wv   = threadIdx.x >> 6;
    const int pix  = blockIdx.x * 64 + lane;
    const float px = (float)(pix & (IW-1)) + 0.5f;
    const float py = (float)(pix >> 8) + 0.5f;
    const float px0  = (float)((blockIdx.x & 3) * 64) + 0.5f;  // strip first px
    const float px63 = px0 + 63.f;

    const float4* __restrict__ gp = (const float4*)sorted;
    const int base = __builtin_amdgcn_readfirstlane(wv) * 256;

    // ---- phase 0: build per-chunk hit masks ----
    unsigned long long mask0, mask1, mask2, mask3;
    {
        const int g0 = base + lane;
        const float4 a0 = gp[(g0      )*3 + 0];
        const float4 c0 = gp[(g0      )*3 + 2];
        const float4 a1 = gp[(g0 +  64)*3 + 0];
        const float4 c1 = gp[(g0 +  64)*3 + 2];
        const float4 a2 = gp[(g0 + 128)*3 + 0];
        const float4 c2 = gp[(g0 + 128)*3 + 2];
        const float4 a3 = gp[(g0 + 192)*3 + 0];
        const float4 c3 = gp[(g0 + 192)*3 + 2];
        mask0 = __ballot((fabsf(py - a0.y) <= c0.w) && (a0.x + c0.z >= px0) && (a0.x - c0.z <= px63));
        mask1 = __ballot((fabsf(py - a1.y) <= c1.w) && (a1.x + c1.z >= px0) && (a1.x - c1.z <= px63));
        mask2 = __ballot((fabsf(py - a2.y) <= c2.w) && (a2.x + c2.z >= px0) && (a2.x - c2.z <= px63));
        mask3 = __ballot((fabsf(py - a3.y) <= c3.w) && (a3.x + c3.z >= px0) && (a3.x - c3.z <= px63));
    }

    // ---- phase 1: composite hits in depth order ----
    float T = 1.f, cr = 0.f, cg = 0.f, cb = 0.f;
    #pragma unroll
    for (int k = 0; k < 4; ++k) {
        unsigned long long m = (k==0) ? mask0 : (k==1) ? mask1 : (k==2) ? mask2 : mask3;
        const int kb = base + k*64;
        while (m) {
            const int b = __builtin_ctzll(m);
            m &= m - 1;
            const int g = kb + b;
            const float4 pa = gp[g*3+0];   // u, v, 0.5*conA, conB
            const float4 pb = gp[g*3+1];   // 0.5*conC, op, smax, col_r
            const float4 pc = gp[g*3+2];   // col_g, col_b, rx, ry
            const float dx = px - pa.x;
            const float dy = py - pa.y;
            const float s1 = pa.z*dx + pa.w*dy;
            const float sigma = fmaf(dx, s1, pb.x*dy*dy);
            if (sigma >= 0.f && sigma <= pb.z) {
                const float al = fminf(0.999f, pb.y * __expf(-sigma));
                if (al >= (1.f/255.f)) {
                    const float w = al * T;
                    cr = fmaf(w, pb.w, cr);
                    cg = fmaf(w, pc.x, cg);
                    cb = fmaf(w, pc.y, cb);
                    T -= w;               // T *= (1-al)
                }
            }
        }
    }

    lds[wv][lane] = make_float4(cr, cg, cb, T);
    __syncthreads();
    if (threadIdx.x < 64) {
        const float4 v0 = lds[0][lane];
        const float4 v1 = lds[1][lane];
        const float4 v2 = lds[2][lane];
        const float4 v3 = lds[3][lane];
        float r = v0.x, g2 = v0.y, b2 = v0.z, Tt = v0.w;
        r = fmaf(Tt, v1.x, r); g2 = fmaf(Tt, v1.y, g2); b2 = fmaf(Tt, v1.z, b2); Tt *= v1.w;
        r = fmaf(Tt, v2.x, r); g2 = fmaf(Tt, v2.y, g2); b2 = fmaf(Tt, v2.z, b2); Tt *= v2.w;
        r = fmaf(Tt, v3.x, r); g2 = fmaf(Tt, v3.y, g2); b2 = fmaf(Tt, v3.z, b2); Tt *= v3.w;
        const int p3 = pix * 3;
        out[p3+0] = fminf(fmaxf(r,  0.f), 1.f);
        out[p3+1] = fminf(fmaxf(g2, 0.f), 1.f);
        out[p3+2] = fminf(fmaxf(b2, 0.f), 1.f);
        out[NPIX*3 + pix] = 1.f - Tt;
    }
}

extern "C" void kernel_launch(void* const* d_in, const int* in_sizes, int n_in,
                              void* d_out, int out_size, void* d_ws, size_t ws_size,
                              hipStream_t stream) {
    const float* means  = (const float*)d_in[0];
    const float* scales = (const float*)d_in[1];
    const float* quats  = (const float*)d_in[2];
    const float* opacs  = (const float*)d_in[3];
    const float* sh0    = (const float*)d_in[4];
    const float* shn    = (const float*)d_in[5];
    const float* times  = (const float*)d_in[6];
    const float* durs   = (const float*)d_in[7];
    const float* vels   = (const float*)d_in[8];
    const float* tptr   = (const float*)d_in[9];
    const float* w2c    = (const float*)d_in[10];
    const float* intr   = (const float*)d_in[11];

    float* ws     = (float*)d_ws;
    float* zc     = ws;                    // 1024 floats
    float* raw    = ws + 1024;             // 1024*12 floats
    float* sorted = ws + 1024 + 12*NG;     // 1024*12 floats

    hipLaunchKernelGGL(k_pre, dim3(16), dim3(64), 0, stream,
                       means, scales, quats, opacs, sh0, shn,
                       times, durs, vels, tptr, w2c, intr, zc, raw);
    hipLaunchKernelGGL(k_rank, dim3(NG), dim3(64), 0, stream, zc, raw, sorted);
    hipLaunchKernelGGL(k_raster, dim3(NPIX/64), dim3(256), 0, stream,
                       sorted, (float*)d_out);
}

// Round 3
// 19.937 us; speedup vs baseline: 5.3358x; 1.0261x over previous
//
#include <hip/hip_runtime.h>
#include <math.h>

#define NG 1024
#define IH 256
#define IW 256
#define NPIX (IH*IW)

// record layout (12 floats / gaussian):
//   rec0 = (u, v, rx, ry)            -- cull
//   rec1 = (0.5*conA, conB, 0.5*conC, smax)
//   rec2 = (op, cr, cg, cb)

// ---------------- Kernel 1: per-Gaussian preprocessing ----------------
__global__ __launch_bounds__(64) void k_pre(
    const float* __restrict__ means, const float* __restrict__ scales,
    const float* __restrict__ quats, const float* __restrict__ opacs,
    const float* __restrict__ sh0, const float* __restrict__ shn,
    const float* __restrict__ times, const float* __restrict__ durs,
    const float* __restrict__ vels, const float* __restrict__ tptr,
    const float* __restrict__ w2c, const float* __restrict__ intr,
    float* __restrict__ zc_out, float* __restrict__ raw)
{
    int g = blockIdx.x * 64 + threadIdx.x;
    if (g >= NG) return;
    const float t = tptr[0];
    const float R00=w2c[0], R01=w2c[1], R02=w2c[2],  tx=w2c[3];
    const float R10=w2c[4], R11=w2c[5], R12=w2c[6],  ty=w2c[7];
    const float R20=w2c[8], R21=w2c[9], R22=w2c[10], tz=w2c[11];
    const float fx=intr[0], cx=intr[2], fy=intr[4], cy=intr[5];

    const float dt = t - times[g];
    const float mx = fmaf(dt, vels[g*3+0], means[g*3+0]);
    const float my = fmaf(dt, vels[g*3+1], means[g*3+1]);
    const float mz = fmaf(dt, vels[g*3+2], means[g*3+2]);

    const float o = opacs[g];
    const float sig_o = 1.f / (1.f + __expf(-o));
    const float ratio = dt * __expf(-durs[g]);
    const float opac = sig_o * __expf(-0.5f * ratio * ratio);

    const float xc = R00*mx + R01*my + R02*mz + tx;
    const float yc = R10*mx + R11*my + R12*mz + ty;
    const float zc = R20*mx + R21*my + R22*mz + tz;
    const float iz = 1.f / zc;
    const float u = fx*xc*iz + cx;
    const float v = fy*yc*iz + cy;

    float qw=quats[g*4+0], qx=quats[g*4+1], qy=quats[g*4+2], qz=quats[g*4+3];
    const float qn = rsqrtf(qw*qw + qx*qx + qy*qy + qz*qz);
    qw*=qn; qx*=qn; qy*=qn; qz*=qn;
    const float sx = __expf(scales[g*3+0]);
    const float sy = __expf(scales[g*3+1]);
    const float sz = __expf(scales[g*3+2]);
    const float G00 = 1.f-2.f*(qy*qy+qz*qz), G01 = 2.f*(qx*qy-qw*qz), G02 = 2.f*(qx*qz+qw*qy);
    const float G10 = 2.f*(qx*qy+qw*qz), G11 = 1.f-2.f*(qx*qx+qz*qz), G12 = 2.f*(qy*qz-qw*qx);
    const float G20 = 2.f*(qx*qz-qw*qy), G21 = 2.f*(qy*qz+qw*qx), G22 = 1.f-2.f*(qx*qx+qy*qy);
    const float M00=G00*sx, M01=G01*sy, M02=G02*sz;
    const float M10=G10*sx, M11=G11*sy, M12=G12*sz;
    const float M20=G20*sx, M21=G21*sy, M22=G22*sz;
    const float W00=R00*M00+R01*M10+R02*M20, W01=R00*M01+R01*M11+R02*M21, W02=R00*M02+R01*M12+R02*M22;
    const float W10=R10*M00+R11*M10+R12*M20, W11=R10*M01+R11*M11+R12*M21, W12=R10*M02+R11*M12+R12*M22;
    const float W20=R20*M00+R21*M10+R22*M20, W21=R20*M01+R21*M11+R22*M21, W22=R20*M02+R21*M12+R22*M22;
    const float xdz = xc*iz, ydz = yc*iz;
    const float fxiz = fx*iz, fyiz = fy*iz;
    const float T00 = fxiz*(W00 - xdz*W20), T01 = fxiz*(W01 - xdz*W21), T02 = fxiz*(W02 - xdz*W22);
    const float T10 = fyiz*(W10 - ydz*W20), T11 = fyiz*(W11 - ydz*W21), T12 = fyiz*(W12 - ydz*W22);
    const float a = T00*T00 + T01*T01 + T02*T02 + 0.3f;
    const float b = T00*T10 + T01*T11 + T02*T12;
    const float c = T10*T10 + T11*T11 + T12*T12 + 0.3f;
    const float det = a*c - b*b;
    const float idet = 1.f / det;
    const float conA = c*idet, conB = -b*idet, conC = a*idet;

    const bool valid = (zc > 0.01f) && (det > 1e-12f);
    const float op_eff = valid ? opac : 0.f;
    const float smax = (op_eff * 255.f > 0.f) ? (logf(op_eff * 255.f) + 1e-4f) : -1e30f;
    float rx, ry;
    if (smax > 0.f) {
        rx = sqrtf(2.f * smax * a) + 0.01f;
        ry = sqrtf(2.f * smax * c) + 0.01f;
    } else {
        rx = -1e30f; ry = -1e30f;
    }

    const float cpx = -(R00*tx + R10*ty + R20*tz);
    const float cpy = -(R01*tx + R11*ty + R21*tz);
    const float cpz = -(R02*tx + R12*ty + R22*tz);
    float dx0 = mx-cpx, dy0 = my-cpy, dz0 = mz-cpz;
    const float dn = rsqrtf(dx0*dx0 + dy0*dy0 + dz0*dz0);
    const float X = dx0*dn, Y = dy0*dn, Z = dz0*dn;
    const float XX=X*X, YY=Y*Y, ZZ=Z*Z;

    float bs[16];
    bs[0]  = 0.28209479177387814f;
    bs[1]  = -0.4886025119029199f * Y;
    bs[2]  =  0.4886025119029199f * Z;
    bs[3]  = -0.4886025119029199f * X;
    bs[4]  =  1.0925484305920792f * X * Y;
    bs[5]  = -1.0925484305920792f * Y * Z;
    bs[6]  =  0.31539156525252005f * (2.f*ZZ - XX - YY);
    bs[7]  = -1.0925484305920792f * X * Z;
    bs[8]  =  0.5462742152960396f * (XX - YY);
    bs[9]  = -0.5900435899266435f * Y * (3.f*XX - YY);
    bs[10] =  2.890611442640554f  * X * Y * Z;
    bs[11] = -0.4570457994644658f * Y * (4.f*ZZ - XX - YY);
    bs[12] =  0.3731763325901154f * Z * (2.f*ZZ - 3.f*XX - 3.f*YY);
    bs[13] = -0.4570457994644658f * X * (4.f*ZZ - XX - YY);
    bs[14] =  1.445305721320277f  * Z * (XX - YY);
    bs[15] = -0.5900435899266435f * X * (XX - 3.f*YY);

    float cr = 0.5f, cg = 0.5f, cb = 0.5f;
    cr = fmaf(bs[0], sh0[g*3+0], cr);
    cg = fmaf(bs[0], sh0[g*3+1], cg);
    cb = fmaf(bs[0], sh0[g*3+2], cb);
    #pragma unroll
    for (int k = 1; k < 16; ++k) {
        const float* s = shn + g*45 + (k-1)*3;
        cr = fmaf(bs[k], s[0], cr);
        cg = fmaf(bs[k], s[1], cg);
        cb = fmaf(bs[k], s[2], cb);
    }
    cr = fmaxf(cr, 0.f); cg = fmaxf(cg, 0.f); cb = fmaxf(cb, 0.f);

    zc_out[g] = zc;
    float* r = raw + g*12;
    r[0] = u;         r[1] = v;    r[2]  = rx;       r[3]  = ry;
    r[4] = 0.5f*conA; r[5] = conB; r[6]  = 0.5f*conC;r[7]  = smax;
    r[8] = op_eff;    r[9] = cr;   r[10] = cg;       r[11] = cb;
}

// ---------------- Kernel 2: stable depth rank + scatter ----------------
__global__ __launch_bounds__(64) void k_rank(
    const float* __restrict__ zc, const float* __restrict__ raw,
    float* __restrict__ sorted)
{
    const int g = blockIdx.x;
    const int lane = threadIdx.x;
    const float myz = zc[g];
    int cnt = 0;
    #pragma unroll
    for (int k = 0; k < 16; ++k) {
        const int j = k*64 + lane;
        const float z = zc[j];
        const bool lt = (z < myz) || (z == myz && j < g);
        cnt += (int)__popcll(__ballot(lt));
    }
    if (lane < 12) sorted[cnt*12 + lane] = raw[g*12 + lane];
}

// ---------------- Kernel 3: rasterize + composite ----------------
// Block = 256 threads = 4 waves; wave = one 256-deep chunk for 64 px of a row.
// Phase 0: one float4 cull load per gaussian -> 4 hit masks per wave.
// Phase 1: per 64-chunk, lanes with a hit bit gather the 48B record into LDS
//          at the bit's prefix-popcount slot (one parallel latency round),
//          then all lanes composite from LDS broadcast reads in bit order
//          (= depth order, since input is depth-sorted).
__global__ __launch_bounds__(256) void k_raster(
    const float* __restrict__ sorted, float* __restrict__ out)
{
    __shared__ float4 hrec[4][64][3];
    __shared__ float4 part[4][64];
    const int lane = threadIdx.x & 63;
    const int wv   = threadIdx.x >> 6;
    const int pix  = blockIdx.x * 64 + lane;
    const float px = (float)(pix & (IW-1)) + 0.5f;
    const float py = (float)(pix >> 8) + 0.5f;
    const float px0  = (float)((blockIdx.x & 3) << 6) + 0.5f;
    const float px63 = px0 + 63.f;

    const float4* __restrict__ gp = (const float4*)sorted;
    const int base = wv * 256;

    // ---- phase 0: cull masks (1 float4 per gaussian) ----
    unsigned long long masks[4];
    #pragma unroll
    for (int k = 0; k < 4; ++k) {
        const float4 r0 = gp[(base + k*64 + lane)*3];
        masks[k] = __ballot((fabsf(py - r0.y) <= r0.w) &&
                            (r0.x + r0.z >= px0) && (r0.x - r0.z <= px63));
    }

    // ---- phase 1: gather + composite per 64-chunk ----
    float T = 1.f, cr = 0.f, cg = 0.f, cb = 0.f;
    #pragma unroll
    for (int k = 0; k < 4; ++k) {
        const unsigned long long m = masks[k];
        if (!m) continue;                      // wave-uniform branch
        const int g = base + k*64 + lane;
        if ((m >> lane) & 1ull) {
            const int pos = (int)__popcll(m & ((1ull << lane) - 1ull));
            hrec[wv][pos][0] = gp[g*3+0];
            hrec[wv][pos][1] = gp[g*3+1];
            hrec[wv][pos][2] = gp[g*3+2];
        }
        asm volatile("s_waitcnt lgkmcnt(0)" ::: "memory");
        const int cnt = (int)__popcll(m);
        for (int i = 0; i < cnt; ++i) {
            const float4 ra = hrec[wv][i][0];  // u, v, rx, ry
            const float4 rb = hrec[wv][i][1];  // 0.5A, B, 0.5C, smax
            const float4 rc = hrec[wv][i][2];  // op, cr, cg, cb
            const float dx = px - ra.x;
            const float dy = py - ra.y;
            const float sigma = fmaf(dx, fmaf(rb.x, dx, rb.y*dy), rb.z*dy*dy);
            if (sigma >= 0.f && sigma <= rb.w) {
                const float al = fminf(0.999f, rc.x * __expf(-sigma));
                if (al >= (1.f/255.f)) {
                    const float w = al * T;
                    cr = fmaf(w, rc.y, cr);
                    cg = fmaf(w, rc.z, cg);
                    cb = fmaf(w, rc.w, cb);
                    T -= w;
                }
            }
        }
    }

    part[wv][lane] = make_float4(cr, cg, cb, T);
    __syncthreads();
    if (threadIdx.x < 64) {
        const float4 v0 = part[0][lane];
        const float4 v1 = part[1][lane];
        const float4 v2 = part[2][lane];
        const float4 v3 = part[3][lane];
        float r = v0.x, g2 = v0.y, b2 = v0.z, Tt = v0.w;
        r = fmaf(Tt, v1.x, r); g2 = fmaf(Tt, v1.y, g2); b2 = fmaf(Tt, v1.z, b2); Tt *= v1.w;
        r = fmaf(Tt, v2.x, r); g2 = fmaf(Tt, v2.y, g2); b2 = fmaf(Tt, v2.z, b2); Tt *= v2.w;
        r = fmaf(Tt, v3.x, r); g2 = fmaf(Tt, v3.y, g2); b2 = fmaf(Tt, v3.z, b2); Tt *= v3.w;
        const int p3 = pix * 3;
        out[p3+0] = fminf(fmaxf(r,  0.f), 1.f);
        out[p3+1] = fminf(fmaxf(g2, 0.f), 1.f);
        out[p3+2] = fminf(fmaxf(b2, 0.f), 1.f);
        out[NPIX*3 + pix] = 1.f - Tt;
    }
}

extern "C" void kernel_launch(void* const* d_in, const int* in_sizes, int n_in,
                              void* d_out, int out_size, void* d_ws, size_t ws_size,
                              hipStream_t stream) {
    const float* means  = (const float*)d_in[0];
    const float* scales = (const float*)d_in[1];
    const float* quats  = (const float*)d_in[2];
    const float* opacs  = (const float*)d_in[3];
    const float* sh0    = (const float*)d_in[4];
    const float* shn    = (const float*)d_in[5];
    const float* times  = (const float*)d_in[6];
    const float* durs   = (const float*)d_in[7];
    const float* vels   = (const float*)d_in[8];
    const float* tptr   = (const float*)d_in[9];
    const float* w2c    = (const float*)d_in[10];
    const float* intr   = (const float*)d_in[11];

    float* ws     = (float*)d_ws;
    float* zc     = ws;                    // 1024 floats
    float* raw    = ws + 1024;             // 1024*12 floats
    float* sorted = ws + 1024 + 12*NG;     // 1024*12 floats

    hipLaunchKernelGGL(k_pre, dim3(16), dim3(64), 0, stream,
                       means, scales, quats, opacs, sh0, shn,
                       times, durs, vels, tptr, w2c, intr, zc, raw);
    hipLaunchKernelGGL(k_rank, dim3(NG), dim3(64), 0, stream, zc, raw, sorted);
    hipLaunchKernelGGL(k_raster, dim3(NPIX/64), dim3(256), 0, stream,
                       sorted, (float*)d_out);
}